// Round 2
// baseline (245.434 us; speedup 1.0000x reference)
//
#include <hip/hip_runtime.h>
#include <hip/hip_bf16.h>

// SrnmSpmm: out[b,s,n] = sum_k x[b,s,keep[k]] * values[n,k] + bias[n]
// keep: cols {8i, 8i+2} of D_IN=4096 -> K=1024. M = B*S = 16384, N = 4096.
//
// R2: pass 1 unchanged (compact+cast x -> bf16 xg, cast values -> bf16).
// Pass 2 upgraded to the 256x256 8-phase schedule (T1 XCD swizzle + T2
// st_16x32 LDS swizzle + T3/T4 counted vmcnt(6) + T5 setprio).

#define M_TOTAL 16384
#define DIN     4096
#define KDIM    1024
#define NDIM    4096

typedef unsigned short u16;
typedef unsigned int   u32;
typedef __bf16 bf16x8 __attribute__((ext_vector_type(8)));
typedef float  f32x4  __attribute__((ext_vector_type(4)));

typedef const void __attribute__((address_space(1)))* gp_t;
typedef void __attribute__((address_space(3)))*       lp_t;

__device__ __forceinline__ u16 f2bf(float f) {
    u32 u = __float_as_uint(f);
    u += 0x7FFFu + ((u >> 16) & 1u);   // round-to-nearest-even
    return (u16)(u >> 16);
}

// Pass 1a: gather kept cols (0,2 of each 8-block) of x, cast to bf16.
__global__ void compact_x_kernel(const float* __restrict__ x,
                                 u32* __restrict__ xg, int nblk) {
    int i = blockIdx.x * blockDim.x + threadIdx.x;
    const int stride = gridDim.x * blockDim.x;
    for (; i < nblk; i += stride) {
        float4 v = *reinterpret_cast<const float4*>(x + (size_t)i * 8);
        xg[i] = (u32)f2bf(v.x) | ((u32)f2bf(v.z) << 16);
    }
}

// Pass 1b: cast values [N][K] fp32 -> bf16.
__global__ void conv_vals_kernel(const float* __restrict__ v,
                                 uint2* __restrict__ vb, int n4) {
    int i = blockIdx.x * blockDim.x + threadIdx.x;
    const int stride = gridDim.x * blockDim.x;
    for (; i < n4; i += stride) {
        float4 f = *reinterpret_cast<const float4*>(v + (size_t)i * 4);
        uint2 o;
        o.x = (u32)f2bf(f.x) | ((u32)f2bf(f.y) << 16);
        o.y = (u32)f2bf(f.z) | ((u32)f2bf(f.w) << 16);
        vb[i] = o;
    }
}

// ---------------- 256x256 8-phase bf16 GEMM ----------------
// C[M][N] = A[M][K] * Bv[N][K]^T + bias.
// 512 threads = 8 waves (2 M x 4 N); wave tile 128x64 = 8x4 16x16 frags.
// K-tile = 64 (two 32-col K-halves). Half-tile = 256 rows x 32 cols bf16
// = 16 KiB, staged by 2 global_load_lds x 512 thr x 16 B.
// LDS 128 KiB: A[dbuf][kh] at (2d+kh)*16KiB, B at +64KiB.
// Subtiled st_16x32 layout per half-tile: addr = (row>>4)*1024 +
// (row&15)*64 + col*2, then XOR bit5 with bit9 (== (row>>3)&1).
// gload_lds dest is linear; the swizzle is applied to the global SOURCE
// per-lane (col ^= 16 elems for lanes>=32) and to the ds_read address.
// Prefetch: half-tile s issued 7 slots before first consumption;
// vmcnt(6)=3 half-tiles outstanding at phases 4 and 8 only.

#define LDSA(d, kh) (((d) * 2 + (kh)) * 16384)
#define LDSB(d, kh) (65536 + ((d) * 2 + (kh)) * 16384)

#define LOADA(d, kh, mh) { _Pragma("unroll") \
    for (int m_ = 0; m_ < 4; ++m_) \
        af[m_] = *(const bf16x8*)(lds + LDSA(d, kh) + (wr * 8 + (mh) * 4 + m_) * 1024 + fl_off); }

#define LOADB(d, kh) { _Pragma("unroll") \
    for (int n_ = 0; n_ < 4; ++n_) \
        bfr[n_] = *(const bf16x8*)(lds + LDSB(d, kh) + (wc * 4 + n_) * 1024 + fl_off); }

#define MFMA16(mh) { \
    __builtin_amdgcn_s_setprio(1); \
    _Pragma("unroll") for (int m_ = 0; m_ < 4; ++m_) \
    _Pragma("unroll") for (int n_ = 0; n_ < 4; ++n_) \
        acc[(mh) * 4 + m_][n_] = __builtin_amdgcn_mfma_f32_16x16x32_bf16( \
            af[m_], bfr[n_], acc[(mh) * 4 + m_][n_], 0, 0, 0); \
    __builtin_amdgcn_s_setprio(0); }

#define BAR() __builtin_amdgcn_s_barrier()
#define VMCNT6() asm volatile("s_waitcnt vmcnt(6)" ::: "memory")
#define VMCNT0() asm volatile("s_waitcnt vmcnt(0)" ::: "memory")

__global__ __launch_bounds__(512, 2) void gemm_kernel(
    const u16* __restrict__ A, const u16* __restrict__ Bv,
    const float* __restrict__ bias, float* __restrict__ C)
{
    __shared__ __align__(1024) char lds[131072];

    const int tid  = threadIdx.x;
    const int lane = tid & 63;
    const int wid  = tid >> 6;
    const int wr   = wid >> 2;      // 0..1
    const int wc   = wid & 3;       // 0..3
    const int lrow = lane & 15;
    const int lg   = lane >> 4;     // 0..3

    // XCD-bijective swizzle (nwg = 1024, divisible by 8)
    const int b   = blockIdx.x;
    const int swz = (b & 7) * 128 + (b >> 3);
    const int btm = swz >> 4;       // 0..63
    const int btn = swz & 15;       // 0..15

    // Staging source (pre-swizzled global address; LDS dest stays linear).
    // Lane covers subtile (i*8 + wid), row (lane>>2), 16 B at col
    // (lane&3)*8 elems, XOR 8-elem block when lane>=32 (bit9->bit5 swz).
    const int st_r0 = wid * 16 + (lane >> 2);
    const int st_ck = ((lane & 3) * 8) ^ ((lane & 32) >> 1);
    const u16* Asrc = A  + (size_t)(btm * 256 + st_r0) * KDIM + st_ck;
    const u16* Bsrc = Bv + (size_t)(btn * 256 + st_r0) * KDIM + st_ck;
    const int dst0 = tid * 16;

    // Fragment ds_read offset within a half-tile (subtiled + swizzled):
    // row&15 = lrow, col*2 = lg*16, XOR bit5 with (lrow>>3)&1.
    const int fl_off = lrow * 64 + ((lg * 16) ^ (((lrow >> 3) & 1) << 5));

    // half-tile s: kt = s>>2, j = s&3 (0=A-kh0, 1=B-kh0, 2=A-kh1, 3=B-kh1)
    auto STAGE = [&](int s) {
        const int kt = s >> 2, j = s & 3;
        const int d = kt & 1, kh = (j >> 1) & 1;
        const int ko = kt * 64 + kh * 32;
        const u16* src = (j & 1) ? Bsrc : Asrc;
        const int base = ((j & 1) ? 65536 : 0) + (d * 2 + kh) * 16384;
        __builtin_amdgcn_global_load_lds((gp_t)(src + ko),
            (lp_t)(lds + base + dst0), 16, 0, 0);
        __builtin_amdgcn_global_load_lds((gp_t)(src + 128 * KDIM + ko),
            (lp_t)(lds + base + 8192 + dst0), 16, 0, 0);
    };

    f32x4 acc[8][4] = {};
    bf16x8 af[4], bfr[4];

    // Prologue: stage K-tile 0 fully + 3 half-tiles of K-tile 1.
    STAGE(0); STAGE(1); STAGE(2); STAGE(3); STAGE(4); STAGE(5); STAGE(6);
    VMCNT6();            // K-tile 0 landed (3 newest half-tiles in flight)
    BAR();

#pragma unroll 1
    for (int t = 0; t < 7; ++t) {
        const int s0 = 8 * t + 7;
        // ---- K-tile 2t (dbuf 0) ----
        LOADB(0, 0); LOADA(0, 0, 0); STAGE(s0);     BAR(); MFMA16(0); BAR();
        LOADA(0, 0, 1);              STAGE(s0 + 1); BAR(); MFMA16(1); BAR();
        LOADB(0, 1); LOADA(0, 1, 0); STAGE(s0 + 2); BAR(); MFMA16(0); BAR();
        LOADA(0, 1, 1);              STAGE(s0 + 3); BAR(); MFMA16(1);
        VMCNT6(); BAR();             // K-tile 2t+1 landed
        // ---- K-tile 2t+1 (dbuf 1) ----
        LOADB(1, 0); LOADA(1, 0, 0); STAGE(s0 + 4); BAR(); MFMA16(0); BAR();
        LOADA(1, 0, 1);              STAGE(s0 + 5); BAR(); MFMA16(1); BAR();
        LOADB(1, 1); LOADA(1, 1, 0); STAGE(s0 + 6); BAR(); MFMA16(0); BAR();
        LOADA(1, 1, 1);              STAGE(s0 + 7); BAR(); MFMA16(1);
        VMCNT6(); BAR();             // K-tile 2t+2 landed
    }
    // ---- last iteration: K-tiles 14 (dbuf 0) and 15 (dbuf 1) ----
    LOADB(0, 0); LOADA(0, 0, 0); STAGE(63);         BAR(); MFMA16(0); BAR();
    LOADA(0, 0, 1);                                 BAR(); MFMA16(1); BAR();
    LOADB(0, 1); LOADA(0, 1, 0);                    BAR(); MFMA16(0); BAR();
    LOADA(0, 1, 1);                                 BAR(); MFMA16(1);
    VMCNT0(); BAR();                 // K-tile 15 fully landed
    LOADB(1, 0); LOADA(1, 0, 0);                    BAR(); MFMA16(0); BAR();
    LOADA(1, 0, 1);                                 BAR(); MFMA16(1); BAR();
    LOADB(1, 1); LOADA(1, 1, 0);                    BAR(); MFMA16(0); BAR();
    LOADA(1, 1, 1);                                 BAR(); MFMA16(1);

    // Epilogue: bias + fp32 store. C/D frag: col = lane&15, row = lg*4 + j.
    const int c_row0 = btm * 256 + wr * 128 + lg * 4;
    const int c_col0 = btn * 256 + wc * 64 + lrow;
    float bv[4];
#pragma unroll
    for (int n = 0; n < 4; ++n) bv[n] = bias[c_col0 + n * 16];
#pragma unroll
    for (int mi = 0; mi < 8; ++mi) {
        const int row = c_row0 + (mi >> 2) * 64 + (mi & 3) * 16;
#pragma unroll
        for (int n = 0; n < 4; ++n) {
#pragma unroll
            for (int j = 0; j < 4; ++j)
                C[(size_t)(row + j) * NDIM + c_col0 + n * 16] = acc[mi][n][j] + bv[n];
        }
    }
}

extern "C" void kernel_launch(void* const* d_in, const int* in_sizes, int n_in,
                              void* d_out, int out_size, void* d_ws, size_t ws_size,
                              hipStream_t stream) {
    const float* x      = (const float*)d_in[0];
    const float* values = (const float*)d_in[1];
    const float* bias   = (const float*)d_in[2];
    float* out = (float*)d_out;

    // ws: xg bf16 [16384][1024] = 32 MB @ 0; values bf16 [4096][1024] @ 32 MB
    u16* xg = (u16*)d_ws;
    u16* vb = (u16*)((char*)d_ws + ((size_t)32 << 20));

    const int nblk = M_TOTAL * (DIN / 8);
    compact_x_kernel<<<2048, 256, 0, stream>>>(x, (u32*)xg, nblk);

    const int n4 = NDIM * KDIM / 4;
    conv_vals_kernel<<<1024, 256, 0, stream>>>(values, (uint2*)vb, n4);

    const int grid = (M_TOTAL / 256) * (NDIM / 256);   // 1024
    gemm_kernel<<<grid, 512, 0, stream>>>(xg, vb, bias, out);
}

// Round 3
// 226.365 us; speedup vs baseline: 1.0842x; 1.0842x over previous
//
#include <hip/hip_runtime.h>
#include <hip/hip_bf16.h>

// SrnmSpmm: out[b,s,n] = sum_k x[b,s,keep[k]] * values[n,k] + bias[n]
// keep: cols {8i, 8i+2} of D_IN=4096 -> K=1024. M = B*S = 16384, N = 4096.
//
// R3: persistent 256-block GEMM (each block: fixed btn, 4 btm tiles, tail of
// tile r prefetches tile r+1's first 7 half-tiles -> no cold prologue/epilogue
// gaps), merged+vectorized pass-1 prep kernel.

#define M_TOTAL 16384
#define DIN     4096
#define KDIM    1024
#define NDIM    4096

typedef unsigned short u16;
typedef unsigned int   u32;
typedef __bf16 bf16x8 __attribute__((ext_vector_type(8)));
typedef float  f32x4  __attribute__((ext_vector_type(4)));

typedef const void __attribute__((address_space(1)))* gp_t;
typedef void __attribute__((address_space(3)))*       lp_t;

__device__ __forceinline__ u16 f2bf(float f) {
    u32 u = __float_as_uint(f);
    u += 0x7FFFu + ((u >> 16) & 1u);   // round-to-nearest-even
    return (u16)(u >> 16);
}
__device__ __forceinline__ u32 pack2(float a, float b) {
    return (u32)f2bf(a) | ((u32)f2bf(b) << 16);
}

// Pass 1 (merged): blocks [0,2048) compact x (4x 8-blocks/thread -> uint4
// write); blocks [2048,2304) cast values (8 floats/thread -> uint4 write).
__global__ void prep_kernel(const float* __restrict__ x, uint4* __restrict__ xg4,
                            const float* __restrict__ vals, uint4* __restrict__ vb4) {
    const int tid = threadIdx.x;
    if (blockIdx.x < 2048) {
        int i = blockIdx.x * 256 + tid;
        const int stride = 2048 * 256;     // nx4 = 2,097,152 = 4*stride exact
#pragma unroll
        for (int it = 0; it < 4; ++it, i += stride) {
            const float* p = x + (size_t)i * 32;
            float4 a = *(const float4*)p;
            float4 b = *(const float4*)(p + 8);
            float4 c = *(const float4*)(p + 16);
            float4 d = *(const float4*)(p + 24);
            xg4[i] = make_uint4(pack2(a.x, a.z), pack2(b.x, b.z),
                                pack2(c.x, c.z), pack2(d.x, d.z));
        }
    } else {
        int i = (blockIdx.x - 2048) * 256 + tid;
        const int stride = 256 * 256;      // nv8 = 524,288 = 8*stride exact
#pragma unroll
        for (int it = 0; it < 8; ++it, i += stride) {
            const float* p = vals + (size_t)i * 8;
            float4 a = *(const float4*)p;
            float4 b = *(const float4*)(p + 4);
            vb4[i] = make_uint4(pack2(a.x, a.y), pack2(a.z, a.w),
                                pack2(b.x, b.y), pack2(b.z, b.w));
        }
    }
}

// ---------------- persistent 256x256 8-phase bf16 GEMM ----------------
// 512 threads = 8 waves (2M x 4N); wave tile 128x64. K-tile 64 (2 K-halves).
// Half-tile 256x32 bf16 = 16 KiB = 2 gload_lds x 512thr x 16B.
// LDS 128 KiB: A[dbuf][kh] @ (2d+kh)*16K, B @ +64K. st_16x32 swizzle applied
// on global SOURCE (gload dest linear) and on ds_read addr. vmcnt counts
// INSTRUCTIONS: vmcnt(6) == all but newest 3 half-tiles landed.

#define LDSA(d, kh) (((d) * 2 + (kh)) * 16384)
#define LDSB(d, kh) (65536 + ((d) * 2 + (kh)) * 16384)

#define LOADA(d, kh, mh) { _Pragma("unroll") \
    for (int m_ = 0; m_ < 4; ++m_) \
        af[m_] = *(const bf16x8*)(lds + LDSA(d, kh) + (wr * 8 + (mh) * 4 + m_) * 1024 + fl_off); }

#define LOADB(d, kh) { _Pragma("unroll") \
    for (int n_ = 0; n_ < 4; ++n_) \
        bfr[n_] = *(const bf16x8*)(lds + LDSB(d, kh) + (wc * 4 + n_) * 1024 + fl_off); }

#define MFMA16(mh) { \
    __builtin_amdgcn_s_setprio(1); \
    _Pragma("unroll") for (int m_ = 0; m_ < 4; ++m_) \
    _Pragma("unroll") for (int n_ = 0; n_ < 4; ++n_) \
        acc[(mh) * 4 + m_][n_] = __builtin_amdgcn_mfma_f32_16x16x32_bf16( \
            af[m_], bfr[n_], acc[(mh) * 4 + m_][n_], 0, 0, 0); \
    __builtin_amdgcn_s_setprio(0); }

#define BAR() __builtin_amdgcn_s_barrier()
#define VMCNT6() asm volatile("s_waitcnt vmcnt(6)" ::: "memory")

__global__ __launch_bounds__(512, 2) void gemm_kernel(
    const u16* __restrict__ A, const u16* __restrict__ Bv,
    const float* __restrict__ bias, float* __restrict__ C)
{
    __shared__ __align__(1024) char lds[131072];

    const int tid  = threadIdx.x;
    const int lane = tid & 63;
    const int wid  = tid >> 6;
    const int wr   = wid >> 2;      // 0..1
    const int wc   = wid & 3;       // 0..3
    const int lrow = lane & 15;
    const int lg   = lane >> 4;     // 0..3

    // Persistent mapping: block bb owns btn=(bb>>3)&15 for all 4 tiles;
    // btm = (bb&7)*8 + (bb>>7) + 2r  (XCD bb&7 shares 8 A-panels across
    // its 32 blocks -> A-panel L2 reuse; B-panel pointer loop-invariant).
    const int bb   = blockIdx.x;
    const int btm0 = (bb & 7) * 8 + (bb >> 7);
    const int btn  = (bb >> 3) & 15;

    // Staging source (pre-swizzled global addr; LDS dest linear).
    const int st_r0 = wid * 16 + (lane >> 2);
    const int st_ck = ((lane & 3) * 8) ^ ((lane & 32) >> 1);
    const u16* A0  = A  + (size_t)(btm0 * 256 + st_r0) * KDIM + st_ck;
    const u16* Bs0 = Bv + (size_t)(btn  * 256 + st_r0) * KDIM + st_ck;
    const int dst0 = tid * 16;

    // Fragment ds_read offset within a half-tile (subtiled + swizzled).
    const int fl_off = lrow * 64 + ((lg * 16) ^ (((lrow >> 3) & 1) << 5));

    // half-tile s (within a tile): kt=s>>2, j=s&3 (0=A.kh0,1=B.kh0,2=A.kh1,3=B.kh1)
    auto STAGE = [&](const u16* as_, int s) {
        const int kt = s >> 2, j = s & 3;
        const int d = kt & 1, kh = (j >> 1) & 1;
        const int ko = kt * 64 + kh * 32;
        const u16* src = (j & 1) ? Bs0 : as_;
        const int base = ((j & 1) ? 65536 : 0) + (d * 2 + kh) * 16384;
        __builtin_amdgcn_global_load_lds((gp_t)(src + ko),
            (lp_t)(lds + base + dst0), 16, 0, 0);
        __builtin_amdgcn_global_load_lds((gp_t)(src + 128 * KDIM + ko),
            (lp_t)(lds + base + 8192 + dst0), 16, 0, 0);
    };

    // bias is loop-invariant (btn fixed): load once.
    const int c_col0 = btn * 256 + wc * 64 + lrow;
    float bvr[4];
#pragma unroll
    for (int n = 0; n < 4; ++n) bvr[n] = bias[c_col0 + n * 16];

    f32x4 acc[8][4] = {};
    bf16x8 af[4], bfr[4];

    // Prologue (once): stage K-tile 0 fully + 3 half-tiles of K-tile 1.
    STAGE(A0, 0); STAGE(A0, 1); STAGE(A0, 2); STAGE(A0, 3);
    STAGE(A0, 4); STAGE(A0, 5); STAGE(A0, 6);
    VMCNT6();                    // s0..s3 landed
    BAR();

#pragma unroll 1
    for (int r = 0; r < 4; ++r) {
        const u16* Ar = A0 + (size_t)r * 512 * KDIM;
        const u16* An = (r < 3) ? (Ar + 512 * KDIM) : Ar;  // r=3: harmless re-stage

#pragma unroll 1
        for (int t = 0; t < 7; ++t) {
            const int s0 = 8 * t + 7;
            // ---- K-tile 2t (dbuf 0) ----
            LOADB(0, 0); LOADA(0, 0, 0); STAGE(Ar, s0);     BAR(); MFMA16(0); BAR();
            LOADA(0, 0, 1);              STAGE(Ar, s0 + 1); BAR(); MFMA16(1); BAR();
            LOADB(0, 1); LOADA(0, 1, 0); STAGE(Ar, s0 + 2); BAR(); MFMA16(0); BAR();
            LOADA(0, 1, 1);              STAGE(Ar, s0 + 3); BAR(); MFMA16(1);
            VMCNT6(); BAR();
            // ---- K-tile 2t+1 (dbuf 1) ----
            LOADB(1, 0); LOADA(1, 0, 0); STAGE(Ar, s0 + 4); BAR(); MFMA16(0); BAR();
            LOADA(1, 0, 1);              STAGE(Ar, s0 + 5); BAR(); MFMA16(1); BAR();
            LOADB(1, 1); LOADA(1, 1, 0); STAGE(Ar, s0 + 6); BAR(); MFMA16(0); BAR();
            LOADA(1, 1, 1);              STAGE(Ar, s0 + 7); BAR(); MFMA16(1);
            VMCNT6(); BAR();
        }
        // ---- tail: K-tiles 14 (dbuf 0) & 15 (dbuf 1); stage slots:
        // s63 (this tile) then n0..n6 (next tile). Each overwrite lands
        // same-phase-after the last ds_read of its region.
        LOADB(0, 0); LOADA(0, 0, 0); STAGE(Ar, 63); BAR(); MFMA16(0); BAR();
        LOADA(0, 0, 1);              STAGE(An, 0);  BAR(); MFMA16(1); BAR();
        LOADB(0, 1); LOADA(0, 1, 0); STAGE(An, 1);  BAR(); MFMA16(0); BAR();
        LOADA(0, 1, 1);              STAGE(An, 2);  BAR(); MFMA16(1);
        VMCNT6(); BAR();             // landed through s63 (K-tile 15 complete)
        LOADB(1, 0); LOADA(1, 0, 0); STAGE(An, 3);  BAR(); MFMA16(0); BAR();
        LOADA(1, 0, 1);              STAGE(An, 4);  BAR(); MFMA16(1); BAR();
        LOADB(1, 1); LOADA(1, 1, 0); STAGE(An, 5);  BAR(); MFMA16(0); BAR();
        LOADA(1, 1, 1);              STAGE(An, 6);  BAR(); MFMA16(1);
        VMCNT6(); BAR();             // landed through n3 (next K-tile 0 ready)

        // Epilogue tile r (no LDS use; next tile's data already in LDS/in flight).
        const int c_row0 = (btm0 + 2 * r) * 256 + wr * 128 + lg * 4;
#pragma unroll
        for (int mi = 0; mi < 8; ++mi) {
            const int row = c_row0 + (mi >> 2) * 64 + (mi & 3) * 16;
#pragma unroll
            for (int n = 0; n < 4; ++n) {
#pragma unroll
                for (int j = 0; j < 4; ++j)
                    C[(size_t)(row + j) * NDIM + c_col0 + n * 16] = acc[mi][n][j] + bvr[n];
                acc[mi][n] = (f32x4){0.f, 0.f, 0.f, 0.f};
            }
        }
    }
}

extern "C" void kernel_launch(void* const* d_in, const int* in_sizes, int n_in,
                              void* d_out, int out_size, void* d_ws, size_t ws_size,
                              hipStream_t stream) {
    const float* x      = (const float*)d_in[0];
    const float* values = (const float*)d_in[1];
    const float* bias   = (const float*)d_in[2];
    float* out = (float*)d_out;

    // ws: xg bf16 [16384][1024] = 32 MB @ 0; values bf16 [4096][1024] @ 32 MB
    u16* xg = (u16*)d_ws;
    u16* vb = (u16*)((char*)d_ws + ((size_t)32 << 20));

    prep_kernel<<<2304, 256, 0, stream>>>(x, (uint4*)xg, values, (uint4*)vb);
    gemm_kernel<<<256, 512, 0, stream>>>(xg, vb, bias, out);
}